// Round 2
// baseline (640.816 us; speedup 1.0000x reference)
//
#include <hip/hip_runtime.h>
#include <stdint.h>

#define DEVI __device__ __forceinline__

typedef __attribute__((ext_vector_type(4))) float     f4v;
typedef __attribute__((ext_vector_type(8))) _Float16  h8;
typedef __attribute__((ext_vector_type(4))) _Float16  h4;
typedef unsigned int  u32;

static constexpr int   TQ = 1024, TKN = 512;
static constexpr float KEY_RATE = 1.385f;
static constexpr float QRY_RATE = 1.0f;
static constexpr float SCALE    = 0.04419417382415922f;   // sqrt(1/512)
static constexpr float INVC     = 0.05190512648261504f;   // log2(10000)/256

// ---------------- workspace layout (bytes) ----------------
static constexpr size_t OFF_MT   = 0;                                  // fp16 [512][512]  Mt[g][h] = (Wq Wk^T)^T
static constexpr size_t OFF_NT   = OFF_MT  + (size_t)512*512*2;        // fp16 [512][512]  Nt[c][h] = (Wv Wo)^T
static constexpr size_t OFF_PEQ  = OFF_NT  + (size_t)512*512*2;        // f32  [1024][512] query pos-enc
static constexpr size_t OFF_W    = OFF_PEQ + (size_t)1024*512*4;       // f32  [512]  w = Wk bq
static constexpr size_t OFF_C    = OFF_W   + 512*4;                    // f32  [512]  c = scale*bv@Wo + bo
static constexpr size_t OFF_BQBK = OFF_C   + 512*4;                    // f32  [1]    bq.bk
static constexpr size_t OFF_T    = OFF_BQBK + 256;                     // f32  [64][512] per-key bias
static constexpr size_t OFF_KP   = OFF_T   + (size_t)64*512*4;         // fp16 [64][512][512]  k' = keys+pe
static constexpr size_t OFF_QPP  = OFF_KP  + (size_t)64*512*512*2;     // fp16 [64][1024][512] q'' = (query+pe)@M
static constexpr size_t OFF_PT   = OFF_QPP + (size_t)64*1024*512*2;    // fp16 [64][512][512]  Pt[c][t] = (values@N)^T
static constexpr size_t WS_NEED  = OFF_PT  + (size_t)64*512*512*2;     // ~131 MB

// ---------------- helpers ----------------
DEVI f4v mfma16(h8 a, h8 b, f4v c) {
  return __builtin_amdgcn_mfma_f32_16x16x32_f16(a, b, c, 0, 0, 0);
}

DEVI void gld16(void* lds, const void* g) {
  __builtin_amdgcn_global_load_lds(
      (const __attribute__((address_space(1))) unsigned int*)g,
      (__attribute__((address_space(3))) unsigned int*)lds, 16, 0, 0);
}

// stage a 128x64 fp16 tile (row-major, row stride ld elems) into LDS, linear dest,
// source pre-swizzled: LDS chunk-slot s of row r holds global chunk s^(r&7).
DEVI void stage_tile(char* ldsdst, const _Float16* src, int ld, int k0, int tid) {
  const int wid = tid >> 6, lane = tid & 63;
#pragma unroll
  for (int it = 0; it < 4; ++it) {
    const int W  = (it << 2) + wid;          // 0..15 wave-chunk
    const int c  = (W << 6) + lane;          // 16B chunk index 0..1023
    const int r  = c >> 3;                   // row 0..127
    const int cc = (c & 7) ^ (r & 7);        // swizzled col-chunk
    gld16(ldsdst + ((size_t)W << 10), src + (size_t)r * ld + k0 + (cc << 3));
  }
}

// reg-stage a 128x64 fp32 tile (row stride 512) -> fp16 LDS with XOR swizzle; optional add table
DEVI void stage_cvt(char* Lb, const float* src, const float* add, int tid, int k0) {
#pragma unroll
  for (int it = 0; it < 8; ++it) {
    const int f = (it << 8) + tid;           // 0..2047 float4 slots
    const int r = f >> 4, fc = f & 15;
    f4v x = *(const f4v*)(src + (size_t)r * 512 + k0 + (fc << 2));
    if (add) {
      f4v av = *(const f4v*)(add + (size_t)r * 512 + k0 + (fc << 2));
      x = x + av;
    }
    h4 o;
#pragma unroll
    for (int i = 0; i < 4; ++i) o[i] = (_Float16)x[i];
    const int addr = ((r << 7) + (fc << 3)) ^ ((r & 7) << 4);
    *(h4*)(Lb + addr) = o;
  }
}

// one K-step of MFMAs: A tile at Lb+0, B tile at Lb+16384 (both 128x64 fp16, swizzled)
DEVI void mfma_step(const char* Lb, int wr, int wc, int lane, f4v (&acc)[4][4]) {
  const int rA = lane & 15;
  const int t0 = (((lane >> 4)     ^ (lane & 7)) << 4);
  const int t1 = ((((lane >> 4)+4) ^ (lane & 7)) << 4);
#pragma unroll
  for (int kk = 0; kk < 2; ++kk) {
    const int tk = kk ? t1 : t0;
    h8 av[4], bv[4];
#pragma unroll
    for (int mi = 0; mi < 4; ++mi)
      av[mi] = *(const h8*)(Lb + ((wr * 64 + mi * 16 + rA) << 7) + tk);
#pragma unroll
    for (int nj = 0; nj < 4; ++nj)
      bv[nj] = *(const h8*)(Lb + 16384 + ((wc * 64 + nj * 16 + rA) << 7) + tk);
#pragma unroll
    for (int mi = 0; mi < 4; ++mi)
#pragma unroll
      for (int nj = 0; nj < 4; ++nj)
        acc[mi][nj] = mfma16(av[mi], bv[nj], acc[mi][nj]);
  }
}

// ---------------- prep kernels ----------------
__global__ void k_prep_vec(const float* __restrict__ Wk, const float* __restrict__ bq,
                           const float* __restrict__ bk, const float* __restrict__ bv,
                           const float* __restrict__ Wo, const float* __restrict__ bo,
                           float* __restrict__ wvec, float* __restrict__ cvec,
                           float* __restrict__ bqbk) {
  const int i = threadIdx.x;  // 512 threads
  float accw = 0.f, accc = 0.f;
  for (int h = 0; h < 512; ++h) accw += Wk[(size_t)i * 512 + h] * bq[h];
  wvec[i] = accw;
  for (int a = 0; a < 512; ++a) accc += bv[a] * Wo[(size_t)a * 512 + i];
  cvec[i] = SCALE * accc + bo[i];
  __shared__ float red[512];
  red[i] = bq[i] * bk[i];
  __syncthreads();
  if (i == 0) { float s = 0.f; for (int h = 0; h < 512; ++h) s += red[h]; bqbk[0] = s; }
}

__global__ void k_prep_peq(const void* __restrict__ fpos_raw, float* __restrict__ PEQ) {
  const u32* fp = (const u32*)fpos_raw;
  const bool is64 = (fp[1] == 0);            // int64 little-endian: hi word of pos[0]
  const int t  = blockIdx.x * 256 + threadIdx.x;  // < 1024*512
  const int tq = t >> 9, d = t & 511;
  const int pos = (int)(is64 ? fp[2 * tq] : fp[tq]);   // batch 0 (positions broadcast)
  float pe = 0.f;
  if (pos != 0) {
    const float invf = exp2f(-(float)(d >> 1) * INVC);
    const float ang  = ((float)pos * QRY_RATE) * invf;
    pe = (d & 1) ? cosf(ang) : sinf(ang);
  }
  PEQ[t] = pe;
}

__global__ __launch_bounds__(256) void k_prep_mats(
    const float* __restrict__ Wq, const float* __restrict__ Wk,
    const float* __restrict__ Wv, const float* __restrict__ Wo,
    _Float16* __restrict__ Mt, _Float16* __restrict__ Nt) {
  __shared__ float ldsK[512], ldsO[512];
  const int j = blockIdx.x, tid = threadIdx.x;
  for (int h = tid; h < 512; h += 256) {
    ldsK[h] = Wk[(size_t)j * 512 + h];
    ldsO[h] = Wo[(size_t)h * 512 + j];
  }
  __syncthreads();
  for (int i = tid; i < 512; i += 256) {
    const f4v* wq = (const f4v*)(Wq + (size_t)i * 512);
    const f4v* wv = (const f4v*)(Wv + (size_t)i * 512);
    float am = 0.f, an = 0.f;
    for (int a4 = 0; a4 < 128; ++a4) {
      const f4v q = wq[a4], v = wv[a4];
      const f4v kk = *(const f4v*)(ldsK + 4 * a4);
      const f4v oo = *(const f4v*)(ldsO + 4 * a4);
      am += q[0]*kk[0] + q[1]*kk[1] + q[2]*kk[2] + q[3]*kk[3];
      an += v[0]*oo[0] + v[1]*oo[1] + v[2]*oo[2] + v[3]*oo[3];
    }
    Mt[(size_t)j * 512 + i] = (_Float16)am;   // Mt[g][h] = sum_a Wk[g,a]*Wq[h,a]
    Nt[(size_t)j * 512 + i] = (_Float16)an;   // Nt[c][h] = sum_a Wv[h,a]*Wo[a,c]
  }
}

__global__ __launch_bounds__(256) void k_prep_keys(
    const float* __restrict__ keys, const void* __restrict__ tpos_raw,
    const float* __restrict__ wvec, const float* __restrict__ bqbk,
    _Float16* __restrict__ kp, float* __restrict__ tvec) {
  const u32* tp = (const u32*)tpos_raw;
  const bool is64 = (tp[1] == 0);
  const int tid = threadIdx.x, wid = tid >> 6, lane = tid & 63;
  const int row = blockIdx.x * 4 + wid;  // < 64*512
  const int pos = (int)(is64 ? tp[2 * row] : tp[row]);
  const int d0  = lane * 8;
  const float* src = keys + (size_t)row * 512 + d0;
  const f4v a = *(const f4v*)src, b = *(const f4v*)(src + 4);
  float x[8] = {a[0], a[1], a[2], a[3], b[0], b[1], b[2], b[3]};
  if (pos != 0) {
    const float pw = (float)pos * KEY_RATE;
#pragma unroll
    for (int u = 0; u < 4; ++u) {
      const float invf = exp2f(-(float)(lane * 4 + u) * INVC);
      const float ang  = pw * invf;
      x[2*u]   += sinf(ang);
      x[2*u+1] += cosf(ang);
    }
  }
  const f4v w0 = *(const f4v*)(wvec + d0), w1 = *(const f4v*)(wvec + d0 + 4);
  float dot = 0.f;
#pragma unroll
  for (int i = 0; i < 4; ++i) dot += x[i] * w0[i] + x[4+i] * w1[i];
#pragma unroll
  for (int off = 32; off; off >>= 1) dot += __shfl_xor(dot, off);
  if (lane == 0) tvec[row] = dot + bqbk[0];
  h8 o;
#pragma unroll
  for (int i = 0; i < 8; ++i) o[i] = (_Float16)x[i];
  *(h8*)(kp + (size_t)row * 512 + d0) = o;
}

// ---------------- GEMM kernels (128x128 tile, BK=64, 4 waves) ----------------
__global__ __launch_bounds__(256, 2) void k_gemm2(
    const float* __restrict__ query, const float* __restrict__ PEQ,
    const _Float16* __restrict__ Mt, _Float16* __restrict__ qpp) {
  __shared__ _Float16 lds[16384];
  char* Lb = (char*)lds;
  const int tid = threadIdx.x, lane = tid & 63, wid = tid >> 6;
  const int wr = wid >> 1, wc = wid & 1;
  const int nt = blockIdx.x;                 // 4 col tiles
  const size_t row_base = (size_t)blockIdx.y * 128;  // 512 row tiles over 65536 rows
  const float* As = query + row_base * 512;
  const float* Ad = PEQ + (size_t)(row_base & 1023) * 512;
  const _Float16* Bs = Mt + (size_t)nt * 128 * 512;
  f4v acc[4][4] = {};
  for (int ks = 0; ks < 8; ++ks) {
    const int k0 = ks * 64;
    stage_tile(Lb + 16384, Bs, 512, k0, tid);
    stage_cvt(Lb, As, Ad, tid, k0);
    asm volatile("s_waitcnt vmcnt(0)" ::: "memory");
    __syncthreads();
    mfma_step(Lb, wr, wc, lane, acc);
    __syncthreads();
  }
#pragma unroll
  for (int mi = 0; mi < 4; ++mi)
#pragma unroll
    for (int nj = 0; nj < 4; ++nj) {
      const int col = nt * 128 + wc * 64 + nj * 16 + (lane & 15);
#pragma unroll
      for (int j = 0; j < 4; ++j) {
        const int row = wr * 64 + mi * 16 + ((lane >> 4) << 2) + j;
        qpp[(row_base + row) * 512 + col] = (_Float16)acc[mi][nj][j];
      }
    }
}

__global__ __launch_bounds__(256, 2) void k_scores(
    const _Float16* __restrict__ qpp, const _Float16* __restrict__ kp,
    float* __restrict__ sout) {
  __shared__ _Float16 lds[16384];
  char* Lb = (char*)lds;
  const int tid = threadIdx.x, lane = tid & 63, wid = tid >> 6;
  const int wr = wid >> 1, wc = wid & 1;
  const int kt = blockIdx.x, qt = blockIdx.y, b = blockIdx.z;
  const _Float16* As = qpp + ((size_t)b * TQ  + qt * 128) * 512;
  const _Float16* Bs = kp  + ((size_t)b * TKN + kt * 128) * 512;
  f4v acc[4][4] = {};
  for (int ks = 0; ks < 8; ++ks) {
    const int k0 = ks * 64;
    stage_tile(Lb,         As, 512, k0, tid);
    stage_tile(Lb + 16384, Bs, 512, k0, tid);
    asm volatile("s_waitcnt vmcnt(0)" ::: "memory");
    __syncthreads();
    mfma_step(Lb, wr, wc, lane, acc);
    __syncthreads();
  }
  float* outp = sout + ((size_t)b * TQ + qt * 128) * TKN + kt * 128;
#pragma unroll
  for (int mi = 0; mi < 4; ++mi)
#pragma unroll
    for (int nj = 0; nj < 4; ++nj) {
      const int colw = wc * 64 + nj * 16 + (lane & 15);
#pragma unroll
      for (int j = 0; j < 4; ++j) {
        const int row = wr * 64 + mi * 16 + ((lane >> 4) << 2) + j;
        outp[(size_t)row * TKN + colw] = acc[mi][nj][j];
      }
    }
}

__global__ __launch_bounds__(256) void k_softmax(
    float* __restrict__ attn, const float* __restrict__ tvec,
    const void* __restrict__ mask_raw) {
  const u32* m32 = (const u32*)mask_raw;
  const bool is32 = (m32[448] != 0);   // int32 layout: element 448 = mask[0][448] = 1; u8 layout: those bytes are 0
  const int tid = threadIdx.x, wid = tid >> 6, lane = tid & 63;
  const int row = blockIdx.x * 4 + wid;   // < 65536
  const int b = row >> 10;
  float* p = attn + (size_t)row * TKN;
  const int k0 = lane * 8;
  f4v v0 = *(f4v*)(p + k0);
  f4v v1 = *(f4v*)(p + k0 + 4);
  const f4v t0 = *(const f4v*)(tvec + b * TKN + k0);
  const f4v t1 = *(const f4v*)(tvec + b * TKN + k0 + 4);
  bool msk[8];
  if (is32) {
    const int base = b * TKN + k0;
#pragma unroll
    for (int i = 0; i < 8; ++i) msk[i] = (m32[base + i] != 0);
  } else {
    const unsigned long long mm =
        *(const unsigned long long*)((const unsigned char*)mask_raw + (size_t)b * TKN + k0);
#pragma unroll
    for (int i = 0; i < 8; ++i) msk[i] = ((mm >> (8 * i)) & 0xffULL) != 0ULL;
  }
  float s[8];
#pragma unroll
  for (int i = 0; i < 4; ++i) { s[i] = v0[i] + t0[i]; s[4+i] = v1[i] + t1[i]; }
  float mx = -INFINITY;
#pragma unroll
  for (int i = 0; i < 8; ++i) if (!msk[i]) mx = fmaxf(mx, s[i]);
#pragma unroll
  for (int off = 32; off; off >>= 1) mx = fmaxf(mx, __shfl_xor(mx, off));
  float sum = 0.f;
#pragma unroll
  for (int i = 0; i < 8; ++i) { const float e = msk[i] ? 0.f : expf(s[i] - mx); s[i] = e; sum += e; }
#pragma unroll
  for (int off = 32; off; off >>= 1) sum += __shfl_xor(sum, off);
  const float r = 1.f / sum;
#pragma unroll
  for (int i = 0; i < 4; ++i) { v0[i] = s[i] * r; v1[i] = s[4+i] * r; }
  *(f4v*)(p + k0) = v0;
  *(f4v*)(p + k0 + 4) = v1;
}

__global__ __launch_bounds__(256, 2) void k_pgemm(
    const float* __restrict__ values, const _Float16* __restrict__ Nt,
    _Float16* __restrict__ Pt) {
  __shared__ _Float16 lds[16384];
  char* Lb = (char*)lds;
  const int tid = threadIdx.x, lane = tid & 63, wid = tid >> 6;
  const int wr = wid >> 1, wc = wid & 1;
  const int nt = blockIdx.x, rt = blockIdx.y, b = blockIdx.z;
  const float* As = values + ((size_t)b * TKN + rt * 128) * 512;
  const _Float16* Bs = Nt + (size_t)nt * 128 * 512;
  f4v acc[4][4] = {};
  for (int ks = 0; ks < 8; ++ks) {
    const int k0 = ks * 64;
    stage_tile(Lb + 16384, Bs, 512, k0, tid);
    stage_cvt(Lb, As, nullptr, tid, k0);
    asm volatile("s_waitcnt vmcnt(0)" ::: "memory");
    __syncthreads();
    mfma_step(Lb, wr, wc, lane, acc);
    __syncthreads();
  }
  _Float16* Pb = Pt + (size_t)b * 512 * 512;
#pragma unroll
  for (int mi = 0; mi < 4; ++mi)
#pragma unroll
    for (int nj = 0; nj < 4; ++nj) {
      const int col   = nt * 128 + wc * 64 + nj * 16 + (lane & 15);
      const int row0g = rt * 128 + wr * 64 + mi * 16 + ((lane >> 4) << 2);
      h4 o;
#pragma unroll
      for (int j = 0; j < 4; ++j) o[j] = (_Float16)acc[mi][nj][j];
      *(h4*)(Pb + (size_t)col * 512 + row0g) = o;   // transposed write: Pt[c][t]
    }
}

__global__ __launch_bounds__(256, 2) void k_final(
    const float* __restrict__ attn, const _Float16* __restrict__ Pt,
    const float* __restrict__ cvec, float* __restrict__ outp) {
  __shared__ _Float16 lds[16384];
  char* Lb = (char*)lds;
  const int tid = threadIdx.x, lane = tid & 63, wid = tid >> 6;
  const int wr = wid >> 1, wc = wid & 1;
  const int nt = blockIdx.x, qt = blockIdx.y, b = blockIdx.z;
  const float* As = attn + ((size_t)b * TQ + qt * 128) * TKN;
  const _Float16* Bs = Pt + (size_t)b * 512 * 512 + (size_t)nt * 128 * 512;
  f4v acc[4][4] = {};
  for (int ks = 0; ks < 8; ++ks) {
    const int k0 = ks * 64;
    stage_tile(Lb + 16384, Bs, 512, k0, tid);
    stage_cvt(Lb, As, nullptr, tid, k0);
    asm volatile("s_waitcnt vmcnt(0)" ::: "memory");
    __syncthreads();
    mfma_step(Lb, wr, wc, lane, acc);
    __syncthreads();
  }
  float* Ob = outp + ((size_t)b * TQ + qt * 128) * 512 + nt * 128;
#pragma unroll
  for (int mi = 0; mi < 4; ++mi)
#pragma unroll
    for (int nj = 0; nj < 4; ++nj) {
      const int colw = wc * 64 + nj * 16 + (lane & 15);
      const float cv = cvec[nt * 128 + colw];
#pragma unroll
      for (int j = 0; j < 4; ++j) {
        const int row = wr * 64 + mi * 16 + ((lane >> 4) << 2) + j;
        Ob[(size_t)row * 512 + colw] = SCALE * acc[mi][nj][j] + cv;
      }
    }
}

// ---------------- launcher ----------------
extern "C" void kernel_launch(void* const* d_in, const int* in_sizes, int n_in,
                              void* d_out, int out_size, void* d_ws, size_t ws_size,
                              hipStream_t stream) {
  (void)in_sizes; (void)n_in; (void)out_size;
  if (ws_size < WS_NEED) return;  // need ~131 MB scratch

  const float* query  = (const float*)d_in[0];
  const float* keys   = (const float*)d_in[1];
  const float* values = (const float*)d_in[2];
  const void*  tpos   = d_in[3];
  const void*  fpos   = d_in[4];
  const void*  mask   = d_in[5];
  const float* Wq = (const float*)d_in[6];
  const float* bq = (const float*)d_in[7];
  const float* Wk = (const float*)d_in[8];
  const float* bk = (const float*)d_in[9];
  const float* Wv = (const float*)d_in[10];
  const float* bv = (const float*)d_in[11];
  const float* Wo = (const float*)d_in[12];
  const float* bo = (const float*)d_in[13];

  char* ws = (char*)d_ws;
  _Float16* Mt   = (_Float16*)(ws + OFF_MT);
  _Float16* Nt   = (_Float16*)(ws + OFF_NT);
  float*    PEQ  = (float*)   (ws + OFF_PEQ);
  float*    wvec = (float*)   (ws + OFF_W);
  float*    cvec = (float*)   (ws + OFF_C);
  float*    bqbk = (float*)   (ws + OFF_BQBK);
  float*    tvec = (float*)   (ws + OFF_T);
  _Float16* kp   = (_Float16*)(ws + OFF_KP);
  _Float16* qpp  = (_Float16*)(ws + OFF_QPP);
  _Float16* Pt   = (_Float16*)(ws + OFF_PT);

  float* outp = (float*)d_out;
  float* attn = outp + (size_t)64 * TQ * 512;   // output 1 region; also scores scratch

  k_prep_vec <<<1, 512, 0, stream>>>(Wk, bq, bk, bv, Wo, bo, wvec, cvec, bqbk);
  k_prep_peq <<<2048, 256, 0, stream>>>(fpos, PEQ);
  k_prep_mats<<<512, 256, 0, stream>>>(Wq, Wk, Wv, Wo, Mt, Nt);
  k_prep_keys<<<8192, 256, 0, stream>>>(keys, tpos, wvec, bqbk, kp, tvec);
  k_gemm2    <<<dim3(4, 512), 256, 0, stream>>>(query, PEQ, Mt, qpp);
  k_scores   <<<dim3(4, 8, 64), 256, 0, stream>>>(qpp, kp, attn);
  k_softmax  <<<16384, 256, 0, stream>>>(attn, tvec, mask);
  k_pgemm    <<<dim3(4, 4, 64), 256, 0, stream>>>(values, Nt, Pt);
  k_final    <<<dim3(4, 8, 64), 256, 0, stream>>>(attn, Pt, cvec, outp);
}

// Round 3
// 491.876 us; speedup vs baseline: 1.3028x; 1.3028x over previous
//
#include <hip/hip_runtime.h>
#include <stdint.h>

#define DEVI __device__ __forceinline__

typedef __attribute__((ext_vector_type(4))) float     f4v;
typedef __attribute__((ext_vector_type(8))) _Float16  h8;
typedef __attribute__((ext_vector_type(4))) _Float16  h4;
typedef unsigned int  u32;

static constexpr int   TQ = 1024, TKN = 512;
static constexpr float KEY_RATE = 1.385f;
static constexpr float QRY_RATE = 1.0f;
static constexpr float SCALE    = 0.04419417382415922f;   // sqrt(1/512)
static constexpr float INVC     = 0.05190512648261504f;   // log2(10000)/256

// ---------------- workspace layout (bytes) ----------------
static constexpr size_t OFF_MT   = 0;                                  // fp16 [512][512]  Mt[g][h]
static constexpr size_t OFF_NT   = OFF_MT  + (size_t)512*512*2;        // fp16 [512][512]  Nt[c][h]
static constexpr size_t OFF_PEQ  = OFF_NT  + (size_t)512*512*2;        // f32  [1024][512]
static constexpr size_t OFF_W    = OFF_PEQ + (size_t)1024*512*4;       // f32  [512]
static constexpr size_t OFF_C    = OFF_W   + 512*4;                    // f32  [512]
static constexpr size_t OFF_BQBK = OFF_C   + 512*4;                    // f32  [1]
static constexpr size_t OFF_T    = OFF_BQBK + 256;                     // f32  [64][512] tvec_eff (mask folded)
static constexpr size_t OFF_KP   = OFF_T   + (size_t)64*512*4;         // fp16 [64][512][512]
static constexpr size_t OFF_QPP  = OFF_KP  + (size_t)64*512*512*2;     // fp16 [64][1024][512]
static constexpr size_t OFF_PT   = OFF_QPP + (size_t)64*1024*512*2;    // fp16 [64][512][512] Pt[c][t]
static constexpr size_t WS_NEED  = OFF_PT  + (size_t)64*512*512*2;

// ---------------- core helpers (BM=128, BN=512, BK=32 template) ----------------
DEVI f4v mfma16(h8 a, h8 b, f4v c) {
  return __builtin_amdgcn_mfma_f32_16x16x32_f16(a, b, c, 0, 0, 0);
}

DEVI void gld16(void* lds, const void* g) {
  __builtin_amdgcn_global_load_lds(
      (const __attribute__((address_space(1))) unsigned int*)g,
      (__attribute__((address_space(3))) unsigned int*)lds, 16, 0, 0);
}

// B panel: 512 rows x 32 cols fp16 (row stride 512), swizzle: slot s holds chunk s^((r>>1)&3)
DEVI void stage_B(char* Bbuf, const _Float16* B, int k0, int tid) {
#pragma unroll
  for (int it = 0; it < 4; ++it) {
    const int c = (it << 9) + tid;              // 0..2047 16B chunks
    const int r = c >> 2, s = c & 3;
    const int sg = s ^ ((r >> 1) & 3);
    gld16(Bbuf + ((size_t)c << 4), B + (size_t)r * 512 + k0 + (sg << 3));
  }
}

// A tile fp16: 128 rows x 32 cols (row stride 512)
DEVI void stage_A16(char* Abuf, const _Float16* A, int k0, int tid) {
  const int r = tid >> 2, s = tid & 3;
  const int sg = s ^ ((r >> 1) & 3);
  gld16(Abuf + ((size_t)tid << 4), A + (size_t)r * 512 + k0 + (sg << 3));
}

// A tile fp32 source: issue loads (early) ...
DEVI void loads_A32(f4v& x0, f4v& x1, const float* A, const float* add, int k0, int tid) {
  const int r = tid >> 2, c8 = (tid & 3) << 3;
  const float* p = A + (size_t)r * 512 + k0 + c8;
  x0 = *(const f4v*)p; x1 = *(const f4v*)(p + 4);
  if (add) {
    const float* q = add + (size_t)r * 512 + k0 + c8;
    x0 += *(const f4v*)q; x1 += *(const f4v*)(q + 4);
  }
}
// ... convert+write (late)
DEVI void write_A32(char* Abuf, f4v x0, f4v x1, int tid) {
  const int r = tid >> 2;
  const int slot = (tid & 3) ^ ((r >> 1) & 3);
  h8 o;
#pragma unroll
  for (int i = 0; i < 4; ++i) { o[i] = (_Float16)x0[i]; o[4 + i] = (_Float16)x1[i]; }
  *(h8*)(Abuf + (r << 6) + (slot << 4)) = o;
}

DEVI void read_frags(const char* Ab, const char* Bb, int wr, int wc, int lane,
                     h8 (&a)[4], h8 (&b)[8]) {
  const int l15 = lane & 15, hi = lane >> 4;
#pragma unroll
  for (int mi = 0; mi < 4; ++mi) {
    const int r = wr * 64 + mi * 16 + l15;
    a[mi] = *(const h8*)(Ab + (r << 6) + ((hi ^ ((r >> 1) & 3)) << 4));
  }
#pragma unroll
  for (int nj = 0; nj < 8; ++nj) {
    const int g = wc * 128 + nj * 16 + l15;
    b[nj] = *(const h8*)(Bb + (g << 6) + ((hi ^ ((g >> 1) & 3)) << 4));
  }
}

#define MFMA_ALL(a, bf, acc)                                   \
  _Pragma("unroll") for (int mi = 0; mi < 4; ++mi)             \
  _Pragma("unroll") for (int nj = 0; nj < 8; ++nj)             \
      acc[mi][nj] = mfma16(a[mi], bf[nj], acc[mi][nj]);

// ---------------- prep kernels ----------------
__global__ void k_prep_vec(const float* __restrict__ Wk, const float* __restrict__ bq,
                           const float* __restrict__ bk, const float* __restrict__ bv,
                           const float* __restrict__ Wo, const float* __restrict__ bo,
                           float* __restrict__ wvec, float* __restrict__ cvec,
                           float* __restrict__ bqbk) {
  const int i = threadIdx.x;  // 512 threads
  float accw = 0.f, accc = 0.f;
  for (int h = 0; h < 512; ++h) accw += Wk[(size_t)i * 512 + h] * bq[h];
  wvec[i] = accw;
  for (int a = 0; a < 512; ++a) accc += bv[a] * Wo[(size_t)a * 512 + i];
  cvec[i] = SCALE * accc + bo[i];
  __shared__ float red[512];
  red[i] = bq[i] * bk[i];
  __syncthreads();
  if (i == 0) { float s = 0.f; for (int h = 0; h < 512; ++h) s += red[h]; bqbk[0] = s; }
}

__global__ void k_prep_peq(const void* __restrict__ fpos_raw, float* __restrict__ PEQ) {
  const u32* fp = (const u32*)fpos_raw;
  const bool is64 = (fp[1] == 0);
  const int t  = blockIdx.x * 256 + threadIdx.x;  // < 1024*512
  const int tq = t >> 9, d = t & 511;
  const int pos = (int)(is64 ? fp[2 * tq] : fp[tq]);
  float pe = 0.f;
  if (pos != 0) {
    const float invf = exp2f(-(float)(d >> 1) * INVC);
    const float ang  = ((float)pos * QRY_RATE) * invf;
    pe = (d & 1) ? cosf(ang) : sinf(ang);
  }
  PEQ[t] = pe;
}

__global__ __launch_bounds__(256) void k_prep_mats(
    const float* __restrict__ Wq, const float* __restrict__ Wk,
    const float* __restrict__ Wv, const float* __restrict__ Wo,
    _Float16* __restrict__ Mt, _Float16* __restrict__ Nt) {
  __shared__ float ldsK[512], ldsO[512];
  const int j = blockIdx.x, tid = threadIdx.x;
  for (int h = tid; h < 512; h += 256) {
    ldsK[h] = Wk[(size_t)j * 512 + h];
    ldsO[h] = Wo[(size_t)h * 512 + j];
  }
  __syncthreads();
  for (int i = tid; i < 512; i += 256) {
    const f4v* wq = (const f4v*)(Wq + (size_t)i * 512);
    const f4v* wv = (const f4v*)(Wv + (size_t)i * 512);
    float am = 0.f, an = 0.f;
    for (int a4 = 0; a4 < 128; ++a4) {
      const f4v q = wq[a4], v = wv[a4];
      const f4v kk = *(const f4v*)(ldsK + 4 * a4);
      const f4v oo = *(const f4v*)(ldsO + 4 * a4);
      am += q[0]*kk[0] + q[1]*kk[1] + q[2]*kk[2] + q[3]*kk[3];
      an += v[0]*oo[0] + v[1]*oo[1] + v[2]*oo[2] + v[3]*oo[3];
    }
    Mt[(size_t)j * 512 + i] = (_Float16)am;
    Nt[(size_t)j * 512 + i] = (_Float16)an;
  }
}

__global__ __launch_bounds__(256) void k_prep_keys(
    const float* __restrict__ keys, const void* __restrict__ tpos_raw,
    const void* __restrict__ mask_raw,
    const float* __restrict__ wvec, const float* __restrict__ bqbk,
    _Float16* __restrict__ kp, float* __restrict__ tvec) {
  const u32* tp = (const u32*)tpos_raw;
  const bool is64 = (tp[1] == 0);
  const int tid = threadIdx.x, wid = tid >> 6, lane = tid & 63;
  const int row = blockIdx.x * 4 + wid;  // < 64*512
  const int pos = (int)(is64 ? tp[2 * row] : tp[row]);
  const int d0  = lane * 8;
  const float* src = keys + (size_t)row * 512 + d0;
  const f4v a = *(const f4v*)src, b = *(const f4v*)(src + 4);
  float x[8] = {a[0], a[1], a[2], a[3], b[0], b[1], b[2], b[3]};
  if (pos != 0) {
    const float pw = (float)pos * KEY_RATE;
#pragma unroll
    for (int u = 0; u < 4; ++u) {
      const float invf = exp2f(-(float)(lane * 4 + u) * INVC);
      const float ang  = pw * invf;
      x[2*u]   += sinf(ang);
      x[2*u+1] += cosf(ang);
    }
  }
  const f4v w0 = *(const f4v*)(wvec + d0), w1 = *(const f4v*)(wvec + d0 + 4);
  float dot = 0.f;
#pragma unroll
  for (int i = 0; i < 4; ++i) dot += x[i] * w0[i] + x[4+i] * w1[i];
#pragma unroll
  for (int off = 32; off; off >>= 1) dot += __shfl_xor(dot, off);
  if (lane == 0) {
    const u32* m32 = (const u32*)mask_raw;
    const bool is32 = (m32[448] != 0);   // int32: mask[0][448]=1; u8: that word = mask[3][256..]=0
    const bool mk = is32 ? (m32[row] != 0)
                         : (((const unsigned char*)mask_raw)[row] != 0);
    tvec[row] = mk ? -1e30f : (dot + bqbk[0]);
  }
  h8 o;
#pragma unroll
  for (int i = 0; i < 8; ++i) o[i] = (_Float16)x[i];
  *(h8*)(kp + (size_t)row * 512 + d0) = o;
}

// ---------------- GEMM kernels: BM=128, BN=512, BK=32, 8 waves, prefetch-pipelined ----------------

// qpp = (query + PEQ) @ M    [65536 x 512] fp16
__global__ __launch_bounds__(512, 2) void k_qk(
    const float* __restrict__ query, const float* __restrict__ PEQ,
    const _Float16* __restrict__ Mt, _Float16* __restrict__ qpp) {
  __shared__ char lds[81920];
  char *Ac = lds, *An = lds + 8192, *Bc = lds + 16384, *Bn = lds + 49152;
  const int tid = threadIdx.x, lane = tid & 63, wid = tid >> 6;
  const int wr = wid >> 2, wc = wid & 3;
  const size_t row_base = (size_t)blockIdx.x * 128;
  const float* As = query + row_base * 512;
  const float* Ad = PEQ + (size_t)(row_base & 1023) * 512;
  f4v acc[4][8] = {};
  f4v x0, x1;
  loads_A32(x0, x1, As, Ad, 0, tid);
  stage_B(Bc, Mt, 0, tid);
  write_A32(Ac, x0, x1, tid);
  __syncthreads();
  for (int ks = 0; ks < 16; ++ks) {
    if (ks < 15) { loads_A32(x0, x1, As, Ad, (ks + 1) * 32, tid); stage_B(Bn, Mt, (ks + 1) * 32, tid); }
    h8 a[4], bf[8];
    read_frags(Ac, Bc, wr, wc, lane, a, bf);
    MFMA_ALL(a, bf, acc);
    if (ks < 15) write_A32(An, x0, x1, tid);
    __syncthreads();
    char* t = Ac; Ac = An; An = t; t = Bc; Bc = Bn; Bn = t;
  }
  const int l15 = lane & 15, hi = lane >> 4;
#pragma unroll
  for (int mi = 0; mi < 4; ++mi)
#pragma unroll
    for (int nj = 0; nj < 8; ++nj) {
      const int col = wc * 128 + nj * 16 + l15;
#pragma unroll
      for (int j = 0; j < 4; ++j) {
        const int row = wr * 64 + mi * 16 + hi * 4 + j;
        qpp[(row_base + row) * 512 + col] = (_Float16)acc[mi][nj][j];
      }
    }
}

// attn = softmax(qpp @ kp^T + tvec_eff)   [fused]
__global__ __launch_bounds__(512, 2) void k_scores(
    const _Float16* __restrict__ qpp, const _Float16* __restrict__ kp,
    const float* __restrict__ tve, float* __restrict__ attn) {
  __shared__ char lds[81920];
  char *Ac = lds, *An = lds + 8192, *Bc = lds + 16384, *Bn = lds + 49152;
  const int tid = threadIdx.x, lane = tid & 63, wid = tid >> 6;
  const int wr = wid >> 2, wc = wid & 3;
  const int qt = blockIdx.x, b = blockIdx.y;
  const _Float16* As = qpp + ((size_t)b * TQ + qt * 128) * 512;
  const _Float16* Bs = kp + (size_t)b * TKN * 512;
  const int l15 = lane & 15, hi = lane >> 4;
  float tv[8];
#pragma unroll
  for (int nj = 0; nj < 8; ++nj) tv[nj] = tve[b * TKN + wc * 128 + nj * 16 + l15];
  f4v acc[4][8] = {};
  stage_A16(Ac, As, 0, tid);
  stage_B(Bc, Bs, 0, tid);
  __syncthreads();
  for (int ks = 0; ks < 16; ++ks) {
    if (ks < 15) { stage_A16(An, As, (ks + 1) * 32, tid); stage_B(Bn, Bs, (ks + 1) * 32, tid); }
    h8 a[4], bf[8];
    read_frags(Ac, Bc, wr, wc, lane, a, bf);
    MFMA_ALL(a, bf, acc);
    __syncthreads();
    char* t = Ac; Ac = An; An = t; t = Bc; Bc = Bn; Bn = t;
  }
  // ---- fused softmax over full 512-wide rows ----
  float* red  = (float*)lds;            // [128][4]
  float* red2 = (float*)(lds + 2048);   // [128][4]
#pragma unroll
  for (int mi = 0; mi < 4; ++mi)
#pragma unroll
    for (int nj = 0; nj < 8; ++nj) {
      const float t = tv[nj];
#pragma unroll
      for (int j = 0; j < 4; ++j) acc[mi][nj][j] += t;
    }
  float mrow[4][4];
#pragma unroll
  for (int mi = 0; mi < 4; ++mi)
#pragma unroll
    for (int j = 0; j < 4; ++j) {
      float m = acc[mi][0][j];
#pragma unroll
      for (int nj = 1; nj < 8; ++nj) m = fmaxf(m, acc[mi][nj][j]);
      m = fmaxf(m, __shfl_xor(m, 1)); m = fmaxf(m, __shfl_xor(m, 2));
      m = fmaxf(m, __shfl_xor(m, 4)); m = fmaxf(m, __shfl_xor(m, 8));
      mrow[mi][j] = m;
    }
  if (l15 == 0) {
#pragma unroll
    for (int mi = 0; mi < 4; ++mi)
#pragma unroll
      for (int j = 0; j < 4; ++j)
        red[(wr * 64 + mi * 16 + hi * 4 + j) * 4 + wc] = mrow[mi][j];
  }
  __syncthreads();
#pragma unroll
  for (int mi = 0; mi < 4; ++mi)
#pragma unroll
    for (int j = 0; j < 4; ++j) {
      const f4v rv = *(const f4v*)(red + (wr * 64 + mi * 16 + hi * 4 + j) * 4);
      mrow[mi][j] = fmaxf(fmaxf(rv[0], rv[1]), fmaxf(rv[2], rv[3]));
    }
  float srow[4][4];
#pragma unroll
  for (int mi = 0; mi < 4; ++mi)
#pragma unroll
    for (int j = 0; j < 4; ++j) {
      float s = 0.f;
      const float m = mrow[mi][j];
#pragma unroll
      for (int nj = 0; nj < 8; ++nj) {
        const float e = expf(acc[mi][nj][j] - m);
        acc[mi][nj][j] = e; s += e;
      }
      s += __shfl_xor(s, 1); s += __shfl_xor(s, 2);
      s += __shfl_xor(s, 4); s += __shfl_xor(s, 8);
      srow[mi][j] = s;
    }
  if (l15 == 0) {
#pragma unroll
    for (int mi = 0; mi < 4; ++mi)
#pragma unroll
      for (int j = 0; j < 4; ++j)
        red2[(wr * 64 + mi * 16 + hi * 4 + j) * 4 + wc] = srow[mi][j];
  }
  __syncthreads();
  float* Ao = attn + ((size_t)b * TQ + qt * 128) * 512;
#pragma unroll
  for (int mi = 0; mi < 4; ++mi)
#pragma unroll
    for (int j = 0; j < 4; ++j) {
      const int row = wr * 64 + mi * 16 + hi * 4 + j;
      const f4v sv = *(const f4v*)(red2 + row * 4);
      const float rinv = 1.f / (sv[0] + sv[1] + sv[2] + sv[3]);
#pragma unroll
      for (int nj = 0; nj < 8; ++nj)
        Ao[(size_t)row * 512 + wc * 128 + nj * 16 + l15] = acc[mi][nj][j] * rinv;
    }
}

// Pt[c][t] = (values @ N)^T per batch   fp16
__global__ __launch_bounds__(512, 2) void k_pv(
    const float* __restrict__ values, const _Float16* __restrict__ Nt,
    _Float16* __restrict__ Pt) {
  __shared__ char lds[81920];
  char *Ac = lds, *An = lds + 8192, *Bc = lds + 16384, *Bn = lds + 49152;
  const int tid = threadIdx.x, lane = tid & 63, wid = tid >> 6;
  const int wr = wid >> 2, wc = wid & 3;
  const int rt = blockIdx.x, b = blockIdx.y;
  const float* As = values + ((size_t)b * TKN + rt * 128) * 512;
  f4v acc[4][8] = {};
  f4v x0, x1;
  loads_A32(x0, x1, As, nullptr, 0, tid);
  stage_B(Bc, Nt, 0, tid);
  write_A32(Ac, x0, x1, tid);
  __syncthreads();
  for (int ks = 0; ks < 16; ++ks) {
    if (ks < 15) { loads_A32(x0, x1, As, nullptr, (ks + 1) * 32, tid); stage_B(Bn, Nt, (ks + 1) * 32, tid); }
    h8 a[4], bf[8];
    read_frags(Ac, Bc, wr, wc, lane, a, bf);
    MFMA_ALL(a, bf, acc);
    if (ks < 15) write_A32(An, x0, x1, tid);
    __syncthreads();
    char* t = Ac; Ac = An; An = t; t = Bc; Bc = Bn; Bn = t;
  }
  const int l15 = lane & 15, hi = lane >> 4;
  _Float16* Pb = Pt + (size_t)b * 512 * 512;
#pragma unroll
  for (int mi = 0; mi < 4; ++mi)
#pragma unroll
    for (int nj = 0; nj < 8; ++nj) {
      const int col = wc * 128 + nj * 16 + l15;
      const int t0  = rt * 128 + wr * 64 + mi * 16 + hi * 4;
      h4 o;
#pragma unroll
      for (int j = 0; j < 4; ++j) o[j] = (_Float16)acc[mi][nj][j];
      *(h4*)(Pb + (size_t)col * 512 + t0) = o;
    }
}

// out = SCALE * attn @ P + cvec
__global__ __launch_bounds__(512, 2) void k_final(
    const float* __restrict__ attn, const _Float16* __restrict__ Pt,
    const float* __restrict__ cvec, float* __restrict__ outp) {
  __shared__ char lds[81920];
  char *Ac = lds, *An = lds + 8192, *Bc = lds + 16384, *Bn = lds + 49152;
  const int tid = threadIdx.x, lane = tid & 63, wid = tid >> 6;
  const int wr = wid >> 2, wc = wid & 3;
  const int qt = blockIdx.x, b = blockIdx.y;
  const float* As = attn + ((size_t)b * TQ + qt * 128) * 512;
  const _Float16* Bs = Pt + (size_t)b * 512 * 512;
  const int l15 = lane & 15, hi = lane >> 4;
  float cv[8];
#pragma unroll
  for (int nj = 0; nj < 8; ++nj) cv[nj] = cvec[wc * 128 + nj * 16 + l15];
  f4v acc[4][8] = {};
  f4v x0, x1;
  loads_A32(x0, x1, As, nullptr, 0, tid);
  stage_B(Bc, Bs, 0, tid);
  write_A32(Ac, x0, x1, tid);
  __syncthreads();
  for (int ks = 0; ks < 16; ++ks) {
    if (ks < 15) { loads_A32(x0, x1, As, nullptr, (ks + 1) * 32, tid); stage_B(Bn, Bs, (ks + 1) * 32, tid); }
    h8 a[4], bf[8];
    read_frags(Ac, Bc, wr, wc, lane, a, bf);
    MFMA_ALL(a, bf, acc);
    if (ks < 15) write_A32(An, x0, x1, tid);
    __syncthreads();
    char* t = Ac; Ac = An; An = t; t = Bc; Bc = Bn; Bn = t;
  }
  float* Ob = outp + ((size_t)b * TQ + qt * 128) * 512;
#pragma unroll
  for (int mi = 0; mi < 4; ++mi)
#pragma unroll
    for (int nj = 0; nj < 8; ++nj) {
      const int col = wc * 128 + nj * 16 + l15;
#pragma unroll
      for (int j = 0; j < 4; ++j) {
        const int row = wr * 64 + mi * 16 + hi * 4 + j;
        Ob[(size_t)row * 512 + col] = SCALE * acc[mi][nj][j] + cv[nj];
      }
    }
}

// ---------------- launcher ----------------
extern "C" void kernel_launch(void* const* d_in, const int* in_sizes, int n_in,
                              void* d_out, int out_size, void* d_ws, size_t ws_size,
                              hipStream_t stream) {
  (void)in_sizes; (void)n_in; (void)out_size;
  if (ws_size < WS_NEED) return;

  const float* query  = (const float*)d_in[0];
  const float* keys   = (const float*)d_in[1];
  const float* values = (const float*)d_in[2];
  const void*  tpos   = d_in[3];
  const void*  fpos   = d_in[4];
  const void*  mask   = d_in[5];
  const float* Wq = (const float*)d_in[6];
  const float* bq = (const float*)d_in[7];
  const float* Wk = (const float*)d_in[8];
  const float* bk = (const float*)d_in[9];
  const float* Wv = (const float*)d_in[10];
  const float* bv = (const float*)d_in[11];
  const float* Wo = (const float*)d_in[12];
  const float* bo = (const float*)d_in[13];

  char* ws = (char*)d_ws;
  _Float16* Mt   = (_Float16*)(ws + OFF_MT);
  _Float16* Nt   = (_Float16*)(ws + OFF_NT);
  float*    PEQ  = (float*)   (ws + OFF_PEQ);
  float*    wvec = (float*)   (ws + OFF_W);
  float*    cvec = (float*)   (ws + OFF_C);
  float*    bqbk = (float*)   (ws + OFF_BQBK);
  float*    tvec = (float*)   (ws + OFF_T);
  _Float16* kp   = (_Float16*)(ws + OFF_KP);
  _Float16* qpp  = (_Float16*)(ws + OFF_QPP);
  _Float16* Pt   = (_Float16*)(ws + OFF_PT);

  float* outp = (float*)d_out;
  float* attn = outp + (size_t)64 * TQ * 512;   // output 1 region

  k_prep_vec <<<1, 512, 0, stream>>>(Wk, bq, bk, bv, Wo, bo, wvec, cvec, bqbk);
  k_prep_peq <<<2048, 256, 0, stream>>>(fpos, PEQ);
  k_prep_mats<<<512, 256, 0, stream>>>(Wq, Wk, Wv, Wo, Mt, Nt);
  k_prep_keys<<<8192, 256, 0, stream>>>(keys, tpos, mask, wvec, bqbk, kp, tvec);
  k_qk       <<<512, 512, 0, stream>>>(query, PEQ, Mt, qpp);
  k_scores   <<<dim3(8, 64), 512, 0, stream>>>(qpp, kp, tvec, attn);
  k_pv       <<<dim3(4, 64), 512, 0, stream>>>(values, Nt, Pt);
  k_final    <<<dim3(8, 64), 512, 0, stream>>>(attn, Pt, cvec, outp);
}

// Round 4
// 359.575 us; speedup vs baseline: 1.7821x; 1.3679x over previous
//
#include <hip/hip_runtime.h>
#include <stdint.h>

#define DEVI __device__ __forceinline__

typedef __attribute__((ext_vector_type(4))) float     f4v;
typedef __attribute__((ext_vector_type(8))) _Float16  h8;
typedef __attribute__((ext_vector_type(4))) _Float16  h4;
typedef unsigned int  u32;

static constexpr int   TQ = 1024, TKN = 512;
static constexpr float KEY_RATE = 1.385f;
static constexpr float QRY_RATE = 1.0f;
static constexpr float SCALE    = 0.04419417382415922f;   // sqrt(1/512)
static constexpr float INVC     = 0.05190512648261504f;   // log2(10000)/256

// ---------------- workspace layout (bytes) ----------------
static constexpr size_t OFF_MM   = 0;                                  // fp16 [512][512]  Mm[c][g] = Wq Wk^T
static constexpr size_t OFF_NT   = OFF_MM  + (size_t)512*512*2;        // fp16 [512][512]  Nt[c][e] = (Wv Wo)^T
static constexpr size_t OFF_WOT  = OFF_NT  + (size_t)512*512*2;        // f32  [512][512]  Wo^T
static constexpr size_t OFF_PEQ  = OFF_WOT + (size_t)512*512*4;        // f32  [1024][512]
static constexpr size_t OFF_W    = OFF_PEQ + (size_t)1024*512*4;       // f32  [512]
static constexpr size_t OFF_C    = OFF_W   + 512*4;                    // f32  [512]
static constexpr size_t OFF_BQBK = OFF_C   + 512*4;                    // f32  [1]
static constexpr size_t OFF_T    = OFF_BQBK + 256;                     // f32  [64][512] tvec_eff
static constexpr size_t OFF_KP   = OFF_T   + (size_t)64*512*4;         // fp16 [64][512][512]
static constexpr size_t OFF_MKT  = OFF_KP  + (size_t)64*512*512*2;     // fp16 [64][512][512] MKt[t][c]
static constexpr size_t OFF_PT   = OFF_MKT + (size_t)64*512*512*2;     // fp16 [64][512][512] Pt[c][t]
static constexpr size_t WS_NEED  = OFF_PT  + (size_t)64*512*512*2;     // ~112 MB
static constexpr size_t OFF_A16  = WS_NEED;                            // fp16 [64][1024][512] attn fp16 copy
static constexpr size_t WS_BIG   = OFF_A16 + (size_t)64*1024*512*2;    // ~180 MB

// ---------------- core helpers (BM=128, BN=512, BK=32 template) ----------------
DEVI f4v mfma16(h8 a, h8 b, f4v c) {
  return __builtin_amdgcn_mfma_f32_16x16x32_f16(a, b, c, 0, 0, 0);
}

DEVI void gld16(void* lds, const void* g) {
  __builtin_amdgcn_global_load_lds(
      (const __attribute__((address_space(1))) unsigned int*)g,
      (__attribute__((address_space(3))) unsigned int*)lds, 16, 0, 0);
}

// B panel: 512 rows x 32 cols fp16 (row stride 512): slot s holds chunk s^((r>>1)&3)
DEVI void stage_B(char* Bbuf, const _Float16* B, int k0, int tid) {
#pragma unroll
  for (int it = 0; it < 4; ++it) {
    const int c = (it << 9) + tid;              // 0..2047 16B chunks
    const int r = c >> 2, s = c & 3;
    const int sg = s ^ ((r >> 1) & 3);
    gld16(Bbuf + ((size_t)c << 4), B + (size_t)r * 512 + k0 + (sg << 3));
  }
}

// A tile fp16: 128 rows x 32 cols (row stride 512)
DEVI void stage_A16(char* Abuf, const _Float16* A, int k0, int tid) {
  const int r = tid >> 2, s = tid & 3;
  const int sg = s ^ ((r >> 1) & 3);
  gld16(Abuf + ((size_t)tid << 4), A + (size_t)r * 512 + k0 + (sg << 3));
}

// A tile fp32 source: issue loads (early) ...
DEVI void loads_A32(f4v& x0, f4v& x1, const float* A, const float* add, int k0, int tid) {
  const int r = tid >> 2, c8 = (tid & 3) << 3;
  const float* p = A + (size_t)r * 512 + k0 + c8;
  x0 = *(const f4v*)p; x1 = *(const f4v*)(p + 4);
  if (add) {
    const float* q = add + (size_t)r * 512 + k0 + c8;
    x0 += *(const f4v*)q; x1 += *(const f4v*)(q + 4);
  }
}
// ... convert+write (late)
DEVI void write_A32(char* Abuf, f4v x0, f4v x1, int tid) {
  const int r = tid >> 2;
  const int slot = (tid & 3) ^ ((r >> 1) & 3);
  h8 o;
#pragma unroll
  for (int i = 0; i < 4; ++i) { o[i] = (_Float16)x0[i]; o[4 + i] = (_Float16)x1[i]; }
  *(h8*)(Abuf + (r << 6) + (slot << 4)) = o;
}

DEVI void read_frags(const char* Ab, const char* Bb, int wr, int wc, int lane,
                     h8 (&a)[4], h8 (&b)[8]) {
  const int l15 = lane & 15, hi = lane >> 4;
#pragma unroll
  for (int mi = 0; mi < 4; ++mi) {
    const int r = wr * 64 + mi * 16 + l15;
    a[mi] = *(const h8*)(Ab + (r << 6) + ((hi ^ ((r >> 1) & 3)) << 4));
  }
#pragma unroll
  for (int nj = 0; nj < 8; ++nj) {
    const int g = wc * 128 + nj * 16 + l15;
    b[nj] = *(const h8*)(Bb + (g << 6) + ((hi ^ ((g >> 1) & 3)) << 4));
  }
}

#define MFMA_ALL(a, bf, acc)                                   \
  _Pragma("unroll") for (int mi = 0; mi < 4; ++mi)             \
  _Pragma("unroll") for (int nj = 0; nj < 8; ++nj)             \
      acc[mi][nj] = mfma16(a[mi], bf[nj], acc[mi][nj]);

// reg-stage f32 tiles for the tiny weight-product GEMM (single-buffered)
DEVI void stage_f32_A(char* Abuf, const float* A, int k0, int tid) {
#pragma unroll
  for (int it = 0; it < 2; ++it) {
    const int idx = (it << 9) + tid;           // 0..1023 f4v slots (128 rows x 8)
    const int r = idx >> 3, c4 = idx & 7;
    f4v x = *(const f4v*)(A + (size_t)r * 512 + k0 + (c4 << 2));
    h4 o;
#pragma unroll
    for (int i = 0; i < 4; ++i) o[i] = (_Float16)x[i];
    const int slot = (c4 >> 1) ^ ((r >> 1) & 3);
    *(h4*)(Abuf + (r << 6) + (slot << 4) + ((c4 & 1) << 3)) = o;
  }
}
DEVI void stage_f32_B(char* Bbuf, const float* B, int k0, int tid) {
#pragma unroll
  for (int it = 0; it < 8; ++it) {
    const int idx = (it << 9) + tid;           // 0..4095 (512 rows x 8)
    const int r = idx >> 3, c4 = idx & 7;
    f4v x = *(const f4v*)(B + (size_t)r * 512 + k0 + (c4 << 2));
    h4 o;
#pragma unroll
    for (int i = 0; i < 4; ++i) o[i] = (_Float16)x[i];
    const int slot = (c4 >> 1) ^ ((r >> 1) & 3);
    *(h4*)(Bbuf + (r << 6) + (slot << 4) + ((c4 & 1) << 3)) = o;
  }
}

// ---------------- prep kernels ----------------
// blocks 0..63: wvec rows (1 row per wave). block 64: cvec + bqbk.
__global__ __launch_bounds__(512) void k_prep_small(
    const float* __restrict__ Wk, const float* __restrict__ bq,
    const float* __restrict__ bk, const float* __restrict__ bv,
    const float* __restrict__ Wo, const float* __restrict__ bo,
    float* __restrict__ wvec, float* __restrict__ cvec, float* __restrict__ bqbk) {
  __shared__ float red[512];
  const int tid = threadIdx.x, wid = tid >> 6, lane = tid & 63;
  if (blockIdx.x < 64) {
    const int row = blockIdx.x * 8 + wid;
    const float* p = Wk + (size_t)row * 512 + lane * 8;
    const f4v a = *(const f4v*)p, c = *(const f4v*)(p + 4);
    const f4v b0 = *(const f4v*)(bq + lane * 8), b1 = *(const f4v*)(bq + lane * 8 + 4);
    float d = a[0]*b0[0]+a[1]*b0[1]+a[2]*b0[2]+a[3]*b0[3]
            + c[0]*b1[0]+c[1]*b1[1]+c[2]*b1[2]+c[3]*b1[3];
#pragma unroll
    for (int off = 32; off; off >>= 1) d += __shfl_xor(d, off);
    if (lane == 0) wvec[row] = d;
  } else {
    float acc = 0.f;
    for (int a = 0; a < 512; ++a) acc += bv[a] * Wo[(size_t)a * 512 + tid];
    cvec[tid] = SCALE * acc + bo[tid];
    red[tid] = bq[tid] * bk[tid];
    __syncthreads();
    if (tid == 0) { float s = 0.f; for (int h = 0; h < 512; ++h) s += red[h]; bqbk[0] = s; }
  }
}

__global__ void k_prep_peq(const void* __restrict__ fpos_raw, float* __restrict__ PEQ) {
  const u32* fp = (const u32*)fpos_raw;
  const bool is64 = (fp[1] == 0);
  const int t  = blockIdx.x * 256 + threadIdx.x;  // < 1024*512
  const int tq = t >> 9, d = t & 511;
  const int pos = (int)(is64 ? fp[2 * tq] : fp[tq]);
  float pe = 0.f;
  if (pos != 0) {
    const float invf = exp2f(-(float)(d >> 1) * INVC);
    const float ang  = ((float)pos * QRY_RATE) * invf;
    pe = (d & 1) ? cosf(ang) : sinf(ang);
  }
  PEQ[t] = pe;
}

__global__ __launch_bounds__(256) void k_wo_t(const float* __restrict__ Wo,
                                              float* __restrict__ WoT) {
  __shared__ float t[32][33];
  const int tx = threadIdx.x, ty = threadIdx.y;
  const int x = blockIdx.x * 32 + tx;
#pragma unroll
  for (int j = 0; j < 4; ++j)
    t[ty + 8 * j][tx] = Wo[(size_t)(blockIdx.y * 32 + ty + 8 * j) * 512 + x];
  __syncthreads();
  const int x2 = blockIdx.y * 32 + tx;
#pragma unroll
  for (int j = 0; j < 4; ++j)
    WoT[(size_t)(blockIdx.x * 32 + ty + 8 * j) * 512 + x2] = t[tx][ty + 8 * j];
}

// y=0: Mm[c][g] = sum_h Wq[c][h] Wk[g][h];  y=1: Nt[c][e] = sum_a WoT[c][a] Wv[e][a]
__global__ __launch_bounds__(512) void k_prep_mats(
    const float* __restrict__ Wq, const float* __restrict__ Wk,
    const float* __restrict__ WoT, const float* __restrict__ Wv,
    _Float16* __restrict__ Mm, _Float16* __restrict__ Nt) {
  __shared__ char lds[40960];
  char *Ab = lds, *Bb = lds + 8192;
  const int tid = threadIdx.x, lane = tid & 63, wid = tid >> 6;
  const int wr = wid >> 2, wc = wid & 3;
  const float* A = (blockIdx.y == 0 ? Wq : WoT) + (size_t)blockIdx.x * 128 * 512;
  const float* B = (blockIdx.y == 0 ? Wk : Wv);
  _Float16* out = (blockIdx.y == 0 ? Mm : Nt) + (size_t)blockIdx.x * 128 * 512;
  f4v acc[4][8] = {};
  for (int ks = 0; ks < 16; ++ks) {
    stage_f32_A(Ab, A, ks * 32, tid);
    stage_f32_B(Bb, B, ks * 32, tid);
    __syncthreads();
    h8 a[4], bf[8];
    read_frags(Ab, Bb, wr, wc, lane, a, bf);
    MFMA_ALL(a, bf, acc);
    __syncthreads();
  }
  const int l15 = lane & 15, hi = lane >> 4;
#pragma unroll
  for (int mi = 0; mi < 4; ++mi)
#pragma unroll
    for (int nj = 0; nj < 8; ++nj) {
      const int col = wc * 128 + nj * 16 + l15;
#pragma unroll
      for (int j = 0; j < 4; ++j) {
        const int row = wr * 64 + mi * 16 + hi * 4 + j;
        out[(size_t)row * 512 + col] = (_Float16)acc[mi][nj][j];
      }
    }
}

__global__ __launch_bounds__(256) void k_prep_keys(
    const float* __restrict__ keys, const void* __restrict__ tpos_raw,
    const void* __restrict__ mask_raw,
    const float* __restrict__ wvec, const float* __restrict__ bqbk,
    _Float16* __restrict__ kp, float* __restrict__ tvec) {
  const u32* tp = (const u32*)tpos_raw;
  const bool is64 = (tp[1] == 0);
  const int tid = threadIdx.x, wid = tid >> 6, lane = tid & 63;
  const int row = blockIdx.x * 4 + wid;  // < 64*512
  const int pos = (int)(is64 ? tp[2 * row] : tp[row]);
  const int d0  = lane * 8;
  const float* src = keys + (size_t)row * 512 + d0;
  const f4v a = *(const f4v*)src, b = *(const f4v*)(src + 4);
  float x[8] = {a[0], a[1], a[2], a[3], b[0], b[1], b[2], b[3]};
  if (pos != 0) {
    const float pw = (float)pos * KEY_RATE;
#pragma unroll
    for (int u = 0; u < 4; ++u) {
      const float invf = exp2f(-(float)(lane * 4 + u) * INVC);
      const float ang  = pw * invf;
      x[2*u]   += sinf(ang);
      x[2*u+1] += cosf(ang);
    }
  }
  const f4v w0 = *(const f4v*)(wvec + d0), w1 = *(const f4v*)(wvec + d0 + 4);
  float dot = 0.f;
#pragma unroll
  for (int i = 0; i < 4; ++i) dot += x[i] * w0[i] + x[4+i] * w1[i];
#pragma unroll
  for (int off = 32; off; off >>= 1) dot += __shfl_xor(dot, off);
  if (lane == 0) {
    const u32* m32 = (const u32*)mask_raw;
    const bool is32 = (m32[448] != 0);
    const bool mk = is32 ? (m32[row] != 0)
                         : (((const unsigned char*)mask_raw)[row] != 0);
    tvec[row] = mk ? -1e30f : (dot + bqbk[0]);
  }
  h8 o;
#pragma unroll
  for (int i = 0; i < 8; ++i) o[i] = (_Float16)x[i];
  *(h8*)(kp + (size_t)row * 512 + d0) = o;
}

// ---------------- main GEMMs ----------------

// MKt[t][c] = sum_g kp[t][g] Mm[c][g]   per batch, fp16 out
__global__ __launch_bounds__(512, 2) void k_mk(
    const _Float16* __restrict__ kp, const _Float16* __restrict__ Mm,
    _Float16* __restrict__ MKt) {
  __shared__ char lds[81920];
  char *Ac = lds, *An = lds + 8192, *Bc = lds + 16384, *Bn = lds + 49152;
  const int tid = threadIdx.x, lane = tid & 63, wid = tid >> 6;
  const int wr = wid >> 2, wc = wid & 3;
  const int tt = blockIdx.x, b = blockIdx.y;
  const _Float16* As = kp + ((size_t)b * TKN + tt * 128) * 512;
  f4v acc[4][8] = {};
  stage_A16(Ac, As, 0, tid);
  stage_B(Bc, Mm, 0, tid);
  __syncthreads();
  for (int ks = 0; ks < 16; ++ks) {
    if (ks < 15) { stage_A16(An, As, (ks + 1) * 32, tid); stage_B(Bn, Mm, (ks + 1) * 32, tid); }
    h8 a[4], bf[8];
    read_frags(Ac, Bc, wr, wc, lane, a, bf);
    MFMA_ALL(a, bf, acc);
    __syncthreads();
    char* t = Ac; Ac = An; An = t; t = Bc; Bc = Bn; Bn = t;
  }
  _Float16* Ob = MKt + (size_t)b * TKN * 512 + (size_t)tt * 128 * 512;
  const int l15 = lane & 15, hi = lane >> 4;
#pragma unroll
  for (int mi = 0; mi < 4; ++mi)
#pragma unroll
    for (int nj = 0; nj < 8; ++nj) {
      const int col = wc * 128 + nj * 16 + l15;
#pragma unroll
      for (int j = 0; j < 4; ++j) {
        const int row = wr * 64 + mi * 16 + hi * 4 + j;
        Ob[(size_t)row * 512 + col] = (_Float16)acc[mi][nj][j];
      }
    }
}

// attn = softmax((query+PEQ) @ MKt^T + tvec);  writes fp32 attn (+ optional fp16 copy)
__global__ __launch_bounds__(512, 2) void k_scores(
    const float* __restrict__ query, const float* __restrict__ PEQ,
    const _Float16* __restrict__ MKt, const float* __restrict__ tve,
    float* __restrict__ attn, _Float16* __restrict__ a16) {
  __shared__ char lds[81920];
  char *Ac = lds, *An = lds + 8192, *Bc = lds + 16384, *Bn = lds + 49152;
  const int tid = threadIdx.x, lane = tid & 63, wid = tid >> 6;
  const int wr = wid >> 2, wc = wid & 3;
  const int qt = blockIdx.x, b = blockIdx.y;
  const float* As = query + ((size_t)b * TQ + qt * 128) * 512;
  const float* Ad = PEQ + (size_t)(qt * 128) * 512;
  const _Float16* Bs = MKt + (size_t)b * TKN * 512;
  const int l15 = lane & 15, hi = lane >> 4;
  float tv[8];
#pragma unroll
  for (int nj = 0; nj < 8; ++nj) tv[nj] = tve[b * TKN + wc * 128 + nj * 16 + l15];
  f4v acc[4][8] = {};
  f4v x0, x1;
  loads_A32(x0, x1, As, Ad, 0, tid);
  stage_B(Bc, Bs, 0, tid);
  write_A32(Ac, x0, x1, tid);
  __syncthreads();
  for (int ks = 0; ks < 16; ++ks) {
    if (ks < 15) { loads_A32(x0, x1, As, Ad, (ks + 1) * 32, tid); stage_B(Bn, Bs, (ks + 1) * 32, tid); }
    h8 a[4], bf[8];
    read_frags(Ac, Bc, wr, wc, lane, a, bf);
    MFMA_ALL(a, bf, acc);
    if (ks < 15) write_A32(An, x0, x1, tid);
    __syncthreads();
    char* t = Ac; Ac = An; An = t; t = Bc; Bc = Bn; Bn = t;
  }
  // ---- fused softmax over full 512-wide rows ----
  float* red  = (float*)lds;            // [128][4]
  float* red2 = (float*)(lds + 2048);   // [128][4]
#pragma unroll
  for (int mi = 0; mi < 4; ++mi)
#pragma unroll
    for (int nj = 0; nj < 8; ++nj) {
      const float t = tv[nj];
#pragma unroll
      for (int j = 0; j < 4; ++j) acc[mi][nj][j] += t;
    }
  float mrow[4][4];
#pragma unroll
  for (int mi = 0; mi < 4; ++mi)
#pragma unroll
    for (int j = 0; j < 4; ++j) {
      float m = acc[mi][0][j];
#pragma unroll
      for (int nj = 1; nj < 8; ++nj) m = fmaxf(m, acc[mi][nj][j]);
      m = fmaxf(m, __shfl_xor(m, 1)); m = fmaxf(m, __shfl_xor(m, 2));
      m = fmaxf(m, __shfl_xor(m, 4)); m = fmaxf(m, __shfl_xor(m, 8));
      mrow[mi][j] = m;
    }
  if (l15 == 0) {
#pragma unroll
    for (int mi = 0; mi < 4; ++mi)
#pragma unroll
      for (int j = 0; j < 4; ++j)
        red[(wr * 64 + mi * 16 + hi * 4 + j) * 4 + wc] = mrow[mi][j];
  }
  __syncthreads();
#pragma unroll
  for (int mi = 0; mi < 4; ++mi)
#pragma unroll
    for (int j = 0; j < 4; ++j) {
      const f4v rv = *(const f4v*)(red + (wr * 64 + mi * 16 + hi * 4 + j) * 4);
      mrow[mi][j] = fmaxf(fmaxf(rv[0], rv[1]), fmaxf(rv[2], rv[3]));
    }
  float srow[4][4];
#pragma unroll
  for (int mi = 0; mi < 4; ++mi)
#pragma unroll
    for (int j = 0; j < 4; ++j) {
      float s = 0.f;
      const float m = mrow[mi][j];
#pragma unroll
      for (int nj = 0; nj < 8; ++nj) {
        const float e = expf(acc[mi][nj][j] - m);
        acc[mi][nj][j] = e; s += e;
      }
      s += __shfl_xor(s, 1); s += __shfl_xor(s, 2);
      s += __shfl_xor(s, 4); s += __shfl_xor(s, 8);
      srow[mi][j] = s;
    }
  if (l15 == 0) {
#pragma unroll
    for (int mi = 0; mi < 4; ++mi)
#pragma unroll
      for (int j = 0; j < 4; ++j)
        red2[(wr * 64 + mi * 16 + hi * 4 + j) * 4 + wc] = srow[mi][j];
  }
  __syncthreads();
  float* Ao = attn + ((size_t)b * TQ + qt * 128) * 512;
  _Float16* Ah = a16 ? a16 + ((size_t)b * TQ + qt * 128) * 512 : nullptr;
#pragma unroll
  for (int mi = 0; mi < 4; ++mi)
#pragma unroll
    for (int j = 0; j < 4; ++j) {
      const int row = wr * 64 + mi * 16 + hi * 4 + j;
      const f4v sv = *(const f4v*)(red2 + row * 4);
      const float rinv = 1.f / (sv[0] + sv[1] + sv[2] + sv[3]);
#pragma unroll
      for (int nj = 0; nj < 8; ++nj) {
        const float v = acc[mi][nj][j] * rinv;
        const int col = wc * 128 + nj * 16 + l15;
        Ao[(size_t)row * 512 + col] = v;
        if (Ah) Ah[(size_t)row * 512 + col] = (_Float16)v;
      }
    }
}

// Pt[c][t] = (values @ N)^T per batch, fp16
__global__ __launch_bounds__(512, 2) void k_pv(
    const float* __restrict__ values, const _Float16* __restrict__ Nt,
    _Float16* __restrict__ Pt) {
  __shared__ char lds[81920];
  char *Ac = lds, *An = lds + 8192, *Bc = lds + 16384, *Bn = lds + 49152;
  const int tid = threadIdx.x, lane = tid & 63, wid = tid >> 6;
  const int wr = wid >> 2, wc = wid & 3;
  const int rt = blockIdx.x, b = blockIdx.y;
  const float* As = values + ((size_t)b * TKN + rt * 128) * 512;
  f4v acc[4][8] = {};
  f4v x0, x1;
  loads_A32(x0, x1, As, nullptr, 0, tid);
  stage_B(Bc, Nt, 0, tid);
  write_A32(Ac, x0, x1, tid);
  __syncthreads();
  for (int ks = 0; ks < 16; ++ks) {
    if (ks < 15) { loads_A32(x0, x1, As, nullptr, (ks + 1) * 32, tid); stage_B(Bn, Nt, (ks + 1) * 32, tid); }
    h8 a[4], bf[8];
    read_frags(Ac, Bc, wr, wc, lane, a, bf);
    MFMA_ALL(a, bf, acc);
    if (ks < 15) write_A32(An, x0, x1, tid);
    __syncthreads();
    char* t = Ac; Ac = An; An = t; t = Bc; Bc = Bn; Bn = t;
  }
  const int l15 = lane & 15, hi = lane >> 4;
  _Float16* Pb = Pt + (size_t)b * 512 * 512;
#pragma unroll
  for (int mi = 0; mi < 4; ++mi)
#pragma unroll
    for (int nj = 0; nj < 8; ++nj) {
      const int col = wc * 128 + nj * 16 + l15;
      const int t0  = rt * 128 + wr * 64 + mi * 16 + hi * 4;
      h4 o;
#pragma unroll
      for (int j = 0; j < 4; ++j) o[j] = (_Float16)acc[mi][nj][j];
      *(h4*)(Pb + (size_t)col * 512 + t0) = o;
    }
}

// out = SCALE * attn @ P + cvec.  A16P: read attn from fp16 copy via gld_lds.
template <int A16P>
__global__ __launch_bounds__(512, 2) void k_final(
    const float* __restrict__ attn, const _Float16* __restrict__ attn16,
    const _Float16* __restrict__ Pt, const float* __restrict__ cvec,
    float* __restrict__ outp) {
  __shared__ char lds[81920];
  char *Ac = lds, *An = lds + 8192, *Bc = lds + 16384, *Bn = lds + 49152;
  const int tid = threadIdx.x, lane = tid & 63, wid = tid >> 6;
  const int wr = wid >> 2, wc = wid & 3;
  const int qt = blockIdx.x, b = blockIdx.y;
  const float* As = attn + ((size_t)b * TQ + qt * 128) * 512;
  const _Float16* As16 = attn16 + ((size_t)b * TQ + qt * 128) * 512;
  const _Float16* Bs = Pt + (size_t)b * 512 * 512;
  const int l15 = lane & 15, hi = lane >> 4;
  float cv[8];
#pragma unroll
  for (int nj = 0; nj < 8; ++nj) cv[nj] = cvec[wc * 128 + nj * 16 + l15];
  f4v acc[4][8] = {};
  f4v x0, x1;
  if (A16P) {
    stage_A16(Ac, As16, 0, tid);
  } else {
    loads_A32(x0, x1, As, nullptr, 0, tid);
  }
  stage_B(Bc, Bs, 0, tid);
  if (!A16P) write_A32(Ac, x0, x1, tid);
  __syncthreads();
  for (int ks = 0; ks < 16; ++ks) {
    if (ks < 15) {
      if (A16P) stage_A16(An, As16, (ks + 1) * 32, tid);
      else      loads_A32(x0, x1, As, nullptr, (ks + 1) * 32, tid);
      stage_B(Bn, Bs, (ks + 1) * 32, tid);
    }
    h8 a[4], bf[8];
    read_frags(Ac, Bc, wr, wc, lane, a, bf);
    MFMA_ALL(a, bf, acc);
    if (!A16P && ks < 15) write_A32(An, x0, x1, tid);
    __syncthreads();
    char* t = Ac; Ac = An; An = t; t = Bc; Bc = Bn; Bn = t;
  }
  float* Ob = outp + ((size_t)b * TQ + qt * 128) * 512;
#pragma unroll
  for (int mi = 0; mi < 4; ++mi)
#pragma unroll
    for (int nj = 0; nj < 8; ++nj) {
      const int col = wc * 128 + nj * 16 + l15;
#pragma unroll
      for (int j = 0; j < 4; ++j) {
        const int row = wr * 64 + mi * 16 + hi * 4 + j;
        Ob[(size_t)row * 512 + col] = SCALE * acc[mi][nj][j] + cv[nj];
      }
    }
}

// ---------------- launcher ----------------
extern "C" void kernel_launch(void* const* d_in, const int* in_sizes, int n_in,
                              void* d_out, int out_size, void* d_ws, size_t ws_size,
                              hipStream_t stream) {
  (void)in_sizes; (void)n_in; (void)out_size;
  if (ws_size < WS_NEED) return;
  const bool big = (ws_size >= WS_BIG);

  const float* query  = (const float*)d_in[0];
  const float* keys   = (const float*)d_in[1];
  const float* values = (const float*)d_in[2];
  const void*  tpos   = d_in[3];
  const void*  fpos   = d_in[4];
  const void*  mask   = d_in[5];
  const float* Wq = (const float*)d_in[6];
  const float* bq = (const float*)d_in[7];
  const float* Wk = (const float*)d_in[8];
  const float* bk = (const float*)d_in[9];
  const float* Wv = (const float*)d_in[10];
  const float* bv = (const float*)d_in[11];
  const float* Wo = (const float*)d_in[12];
  const float* bo = (const float*)d_in[13];

  char* ws = (char*)d_ws;
  _Float16* Mm   = (_Float16*)(ws + OFF_MM);
  _Float16* Nt   = (_Float16*)(ws + OFF_NT);
  float*    WoT  = (float*)   (ws + OFF_WOT);
  float*    PEQ  = (float*)   (ws + OFF_PEQ);
  float*    wvec = (float*)   (ws + OFF_W);
  float*    cvec = (float*)   (ws + OFF_C);
  float*    bqbk = (float*)   (ws + OFF_BQBK);
  float*    tvec = (float*)   (ws + OFF_T);
  _Float16* kp   = (_Float16*)(ws + OFF_KP);
  _Float16* MKt  = (_Float16*)(ws + OFF_MKT);
  _Float16* Pt   = (_Float16*)(ws + OFF_PT);
  _Float16* a16  = big ? (_Float16*)(ws + OFF_A16) : nullptr;

  float* outp = (float*)d_out;
  float* attn = outp + (size_t)64 * TQ * 512;   // output 1 region

  k_prep_small<<<65, 512, 0, stream>>>(Wk, bq, bk, bv, Wo, bo, wvec, cvec, bqbk);
  k_prep_peq  <<<2048, 256, 0, stream>>>(fpos, PEQ);
  k_wo_t      <<<dim3(16, 16), dim3(32, 8), 0, stream>>>(Wo, WoT);
  k_prep_mats <<<dim3(4, 2), 512, 0, stream>>>(Wq, Wk, WoT, Wv, Mm, Nt);
  k_prep_keys <<<8192, 256, 0, stream>>>(keys, tpos, mask, wvec, bqbk, kp, tvec);
  k_mk        <<<dim3(4, 64), 512, 0, stream>>>(kp, Mm, MKt);
  k_scores    <<<dim3(8, 64), 512, 0, stream>>>(query, PEQ, MKt, tvec, attn, a16);
  k_pv        <<<dim3(4, 64), 512, 0, stream>>>(values, Nt, Pt);
  if (big) k_final<1><<<dim3(8, 64), 512, 0, stream>>>(attn, a16, Pt, cvec, outp);
  else     k_final<0><<<dim3(8, 64), 512, 0, stream>>>(attn, a16, Pt, cvec, outp);
}